// Round 9
// baseline (260.733 us; speedup 1.0000x reference)
//
#include <hip/hip_runtime.h>
#include <hip/hip_fp16.h>

#define BB 2
#define AA 512
#define NN 1024
#define FF 64
#define DIN 128
#define DOUT 128
#define TH 25
#define ASTRIDE 40   // halves per a_tile row (16B-aligned frag base)
#define NSPLIT 2
#define NIT 8        // NN / (16 * 4 * NSPLIT) tiles per wave

typedef _Float16 half8 __attribute__((ext_vector_type(8)));
typedef _Float16 half4v __attribute__((ext_vector_type(4)));
typedef float floatx4 __attribute__((ext_vector_type(4)));

#define LOG2E 1.44269504088896f
#define LN2F  0.693147180559945f

__device__ __forceinline__ float ssp_f(float x) {
    return __logf(0.5f * __expf(x) + 0.5f);  // softplus(x) - ln2
}

__device__ __forceinline__ float cutcos(float r) {
    float c = 0.5f * (__cosf(r * (3.14159265358979323846f / 5.0f)) + 1.0f);
    return (r < 5.0f) ? c : 0.0f;
}

// folded shifted softplus: input z = a*log2e - 1 (scale/shift folded into W1/b1),
// output log2(0.5*e^a + 0.5) = ssp(a)/ln2 (ln2 folded into W2 rows).
__device__ __forceinline__ __half2 ssp2f(__half2 z) {
    const __half2 hlf = __float2half2_rn(0.5f);
    return h2log2(__hadd2(h2exp2(z), hlf));
}

// pack two f32 -> __half2 (v_cvt_pkrtz_f16_f32); bit-cast through memory
__device__ __forceinline__ __half2 pk2(float a, float b) {
    auto v = __builtin_amdgcn_cvt_pkrtz(a, b);  // __fp16 ext_vector(2)
    __half2 r;
    __builtin_memcpy(&r, &v, sizeof(r));
    return r;
}

// pack four half2 -> half8 (register concat for MFMA operand)
__device__ __forceinline__ half8 pack8(__half2 a, __half2 b, __half2 c, __half2 d) {
    half8 r;
    __builtin_memcpy(reinterpret_cast<char*>(&r) + 0,  &a, 4);
    __builtin_memcpy(reinterpret_cast<char*>(&r) + 4,  &b, 4);
    __builtin_memcpy(reinterpret_cast<char*>(&r) + 8,  &c, 4);
    __builtin_memcpy(reinterpret_cast<char*>(&r) + 12, &d, 4);
    return r;
}

// ---- d_ws layout (bytes) ----
#define OFF_Y       0                                              // 128 KB
#define OFF_PARTIAL (OFF_Y + (size_t)BB * AA * FF * 2)             // 512 KB (NSPLIT=2)
#define OFF_B1      (OFF_PARTIAL + (size_t)NSPLIT * BB * AA * FF * 4)
#define OFF_B2      (OFF_B1 + 4 * 64 * 8 * 2)                      // B1tab 4 KB
#define OFF_BP      (OFF_B2 + 8 * 64 * 8 * 2)                      // B2tab 8 KB; BPtab(b2) 2 KB

// Kernel 1: in2f (all blocks) + weight-fragment prep (block 0 only).
// mm1 feature PERMUTATION (verified R2/R3): block g, D-row m -> feature
// base_g + 8*(m>>2) + (m&3), base = {0,4,32,36}; this makes mm1's per-lane D
// registers exactly mm2's B-operand fragment in natural f1 order (no LDS trip).
// Folds (verified R6): W_t1 *= log2e; B1 row k=25 = b_t1[feat]*log2e - 1
// (A col 25 = 1.0) so mm1's accumulator directly yields z for ssp2f;
// W_t2 *= ln2 restores scale.
__global__ void in2f_prep_kernel(const float* __restrict__ x,
                                 const float* __restrict__ Wi,
                                 _Float16* __restrict__ y,
                                 const float* __restrict__ W_t1, const float* __restrict__ b_t1,
                                 const float* __restrict__ W_t2, const float* __restrict__ b_t2,
                                 _Float16* __restrict__ B1tab, _Float16* __restrict__ B2tab,
                                 _Float16* __restrict__ BPtab) {
    __shared__ float xs[DIN];
    const int ba = blockIdx.x;
    const int t = threadIdx.x;  // 64
    xs[t] = x[ba * DIN + t];
    xs[t + 64] = x[ba * DIN + 64 + t];
    __syncthreads();
    float acc = 0.f;
#pragma unroll 8
    for (int d = 0; d < DIN; ++d) acc += xs[d] * Wi[d * FF + t];
    y[ba * FF + t] = (_Float16)acc;

    if (ba == 0) {  // prep: format MFMA fragments in per-lane layout
        const int lane = t, quad = t >> 4, l16 = t & 15;
        const int baseg[4] = {0, 4, 32, 36};
#pragma unroll
        for (int g = 0; g < 4; ++g) {
            // B1: A-row l16 of block g holds PERMUTED feature (fold incl. bias row)
            const int feat_m = baseg[g] + 8 * (l16 >> 2) + (l16 & 3);
#pragma unroll
            for (int j = 0; j < 8; ++j) {
                int k = quad * 8 + j;
                _Float16 v;
                if (k < TH)       v = (_Float16)(W_t1[k * FF + feat_m] * LOG2E);
                else if (k == TH) v = (_Float16)(b_t1[feat_m] * LOG2E - 1.0f);  // bias row (A col 25 = 1)
                else              v = (_Float16)0.f;
                B1tab[(g * 64 + lane) * 8 + j] = v;
            }
            // b2 pairs for native mm2 D rows 4*quad+{2e,2e+1}: feat g*16+quad*4+...
#pragma unroll
            for (int e = 0; e < 2; ++e) {
                BPtab[((g * 2 + e) * 64 + lane) * 2 + 0] =
                    (_Float16)b_t2[g * 16 + quad * 4 + 2 * e];
                BPtab[((g * 2 + e) * 64 + lane) * 2 + 1] =
                    (_Float16)b_t2[g * 16 + quad * 4 + 2 * e + 1];
            }
            // B2 natural k-order (matches permuted-mm1 output), rows scaled by ln2
#pragma unroll
            for (int q = 0; q < 2; ++q)
#pragma unroll
                for (int j = 0; j < 8; ++j)
                    B2tab[((g * 2 + q) * 64 + lane) * 8 + j] =
                        (_Float16)(W_t2[(q * 32 + quad * 8 + j) * FF + g * 16 + l16] * LN2F);
        }
    }
}

// Kernel 2: R6 config (NSPLIT=2/NIT=8, folded ssp, coalesced LDS A-staging)
// with BOTH inter-matmul LDS round trips removed:
//  - mm1 -> mm2 in registers via the feature permutation (h_tile deleted)
//  - mm2 output consumed in its NATIVE D layout: lane (quad,l16) owns triple
//    l16, feats g*16+quad*4+r; y gathered as 8B half4 per g (same cache-line
//    count as the 16B gather layout: quad-chunks of one triple share lines)
// DS ops/iter: 20 -> 8 (7 A-writes + 1 afrag read). f-read 8-way bank
// conflicts gone. LDS/block 15.4 KB -> ~6.4 KB.
// NOTE: bare __launch_bounds__(256) — forcing caps spills (R7: 27 MB scratch).
__global__ __launch_bounds__(256) void triple_kernel(
    const int* __restrict__ nbrj, const int* __restrict__ nbrk,
    const float* __restrict__ r_ij, const float* __restrict__ r_ik,
    const float* __restrict__ tmask, const float* __restrict__ d_ijk,
    const _Float16* __restrict__ B1tab, const _Float16* __restrict__ B2tab,
    const _Float16* __restrict__ BPtab,
    const _Float16* __restrict__ y_tab, float* __restrict__ partial) {

    // per-wave a_tile -> no __syncthreads in main loop (same-wave DS in-order)
    __shared__ __align__(16) _Float16 a_tile[4][16 * ASTRIDE];
    __shared__ float red[4][FF];

    const int blk = blockIdx.x;
    const int ba = blk >> 1;         // NSPLIT = 2
    const int split = blk & 1;
    const int b = ba >> 9;  // A = 512
    const int tid = threadIdx.x;
    const int w = tid >> 6;
    const int lane = tid & 63;
    const int quad = lane >> 4;
    const int l16 = lane & 15;

    const long ban = (long)ba * NN;
    const float* dbase = d_ijk + (long)ba * NN * TH;
    const _Float16* yb = y_tab + (long)b * (AA * FF);

    // ---- persistent weights: B1 perm (16) + B2 (32) + b2 pairs (8) ----
    half8 B1[4];
    half8 B2[4][2];
    __half2 b2p[4][2];
#pragma unroll
    for (int g = 0; g < 4; ++g) {
        B1[g] = *(const half8*)(B1tab + (g * 64 + lane) * 8);
        B2[g][0] = *(const half8*)(B2tab + ((g * 2 + 0) * 64 + lane) * 8);
        B2[g][1] = *(const half8*)(B2tab + ((g * 2 + 1) * 64 + lane) * 8);
#pragma unroll
        for (int e = 0; e < 2; ++e)
            b2p[g][e] = *(const __half2*)(BPtab + ((g * 2 + e) * 64 + lane) * 2);
    }

    // ---- per-lane triple precompute, TWO sets, PACKED (R8-verified):
    //      set0: lane (quad,l16) owns triple l16 of tile (split*32 + quad*4 + w)
    //      set1: same tile +16 (triple +256). Iteration it reads via shfl from
    //      source lane (it&3)*16 + l16 (set = it>=4).
    const int tile0 = split * 32 + quad * 4 + w;
    const long n0a = ban + (long)tile0 * 16 + l16;
    const long n1a = n0a + 256;
    int pp0, pp1, wp0, wp1;
    {
        const float rij0 = r_ij[n0a], rik0 = r_ik[n0a];
        const float rij1 = r_ij[n1a], rik1 = r_ik[n1a];
        const float iv0 = cutcos(rij0) * cutcos(rik0) * tmask[n0a] / (rij0 + rik0);
        const float iv1 = cutcos(rij1) * cutcos(rik1) * tmask[n1a] / (rij1 + rik1);
        __half2 w0 = pk2(rij0 * iv0, rik0 * iv0);
        __half2 w1 = pk2(rij1 * iv1, rik1 * iv1);
        __builtin_memcpy(&wp0, &w0, 4);
        __builtin_memcpy(&wp1, &w1, 4);
        pp0 = nbrj[n0a] | (nbrk[n0a] << 16);   // indices < 512 -> 16 bits each
        pp1 = nbrj[n1a] | (nbrk[n1a] << 16);
    }

    // A-tile K-pad: col 25 = 1.0 (bias row), cols 26..31 = 0 — written once
    for (int idx = lane; idx < 16 * 7; idx += 64) {
        int r = idx / 7, c = 25 + idx % 7;
        a_tile[w][r * ASTRIDE + c] = (c == 25) ? (_Float16)1.f : (_Float16)0.f;
    }

    // A staging map: 400 contiguous floats; 3 x float2/lane + 16-float tail
    int lofs2[3][2];
#pragma unroll
    for (int m = 0; m < 3; ++m)
#pragma unroll
        for (int e = 0; e < 2; ++e) {
            int s = m * 128 + lane * 2 + e;
            int r = s / TH, c = s - r * TH;
            lofs2[m][e] = r * ASTRIDE + c;
        }
    const int tofs = 15 * ASTRIDE + 9 + lane;  // tail: row 15 cols 9..24 (lane<16)

    float acc[16];
#pragma unroll
    for (int i = 0; i < 16; ++i) acc[i] = 0.f;
    const floatx4 zero4 = {0.f, 0.f, 0.f, 0.f};

    // ---- prologue: prefetch A tile for it=0 ----
    float2 pA[3];
    float pT = 0.f;
    const float* dp0 = dbase + (long)(split * 32 + w) * 16 * TH;
    {
#pragma unroll
        for (int m = 0; m < 3; ++m) pA[m] = *(const float2*)(dp0 + m * 128 + lane * 2);
        if (lane < 16) pT = dp0[384 + lane];
    }

#pragma unroll 1
    for (int it = 0; it < NIT; ++it) {
        // 1. packed indices/weights via cross-lane broadcast; issue 8B gathers
        //    in the NATIVE layout: lane (quad,l16) needs triple l16's feats
        //    g*16+quad*4..+3 -> 4+4 half4 loads, issued early, used at mm2.
        const bool s1 = (it >= 4);
        const int sl = (it & 3) * 16 + l16;
        const int ppS = s1 ? pp1 : pp0;
        const int wpS = s1 ? wp1 : wp0;
        const int ppa = __shfl(ppS, sl);
        const int wpa = __shfl(wpS, sl);
        const int pj = ppa & 0xffff, pk = ((unsigned)ppa) >> 16;
        const _Float16* yjb = yb + pj * FF + quad * 4;
        const _Float16* ykb = yb + pk * FF + quad * 4;
        half4v yj[4], yk[4];
#pragma unroll
        for (int g = 0; g < 4; ++g) {
            yj[g] = *(const half4v*)(yjb + g * 16);
            yk[g] = *(const half4v*)(ykb + g * 16);
        }

        // 2. commit prefetched A -> LDS (f32 -> f16)
#pragma unroll
        for (int m = 0; m < 3; ++m) {
            a_tile[w][lofs2[m][0]] = (_Float16)pA[m].x;
            a_tile[w][lofs2[m][1]] = (_Float16)pA[m].y;
        }
        if (lane < 16) a_tile[w][tofs] = (_Float16)pT;

        // 3. prefetch next A tile (overlaps MFMA/ssp chain); +4 tiles = +1600 floats
        if (it + 1 < NIT) {
            const float* dn = dp0 + (it + 1) * 1600;
#pragma unroll
            for (int m = 0; m < 3; ++m) pA[m] = *(const float2*)(dn + m * 128 + lane * 2);
            if (lane < 16) pT = dn[384 + lane];
        }

        // unpack interp weights (splat low/high halves)
        __half2 wv;
        __builtin_memcpy(&wv, &wpa, 4);
        const __half2 wj = __half2half2(__low2half(wv));
        const __half2 wk = __half2half2(__high2half(wv));

        // 4. mm1 (swapped, PERMUTED, bias+log2e folded) + folded packed ssp —
        //    output stays in registers; permuted feats make hh exactly mm2's
        //    B-fragment in natural k order (single a-trip is the only DS use)
        half8 afrag = *(const half8*)&a_tile[w][l16 * ASTRIDE + quad * 8];
        __half2 hh[8];
#pragma unroll
        for (int g = 0; g < 4; ++g) {
            floatx4 hv = __builtin_amdgcn_mfma_f32_16x16x32_f16(B1[g], afrag, zero4, 0, 0, 0);
            hh[2 * g]     = ssp2f(pk2(hv[0], hv[1]));
            hh[2 * g + 1] = ssp2f(pk2(hv[2], hv[3]));
        }
        const half8 a2q0 = pack8(hh[0], hh[1], hh[2], hh[3]);
        const half8 a2q1 = pack8(hh[4], hh[5], hh[6], hh[7]);

        // 5. mm2 (K=64, swapped; W2 pre-scaled by ln2) + epilogue in NATIVE
        //    D layout: lane (quad,l16) = triple l16, feats g*16+quad*4+r.
        //    filter = w2 + b2; fv = wj*yj + wk*yk; acc += f16(filter)*fv.
#pragma unroll
        for (int g = 0; g < 4; ++g) {
            floatx4 w2 = __builtin_amdgcn_mfma_f32_16x16x32_f16(B2[g][0], a2q0, zero4, 0, 0, 0);
            w2 = __builtin_amdgcn_mfma_f32_16x16x32_f16(B2[g][1], a2q1, w2, 0, 0, 0);
            const __half2* yj2 = (const __half2*)&yj[g];
            const __half2* yk2 = (const __half2*)&yk[g];
            __half2 f01 = __hadd2(pk2(w2[0], w2[1]), b2p[g][0]);
            __half2 f23 = __hadd2(pk2(w2[2], w2[3]), b2p[g][1]);
            __half2 fv01 = __hfma2(wj, yj2[0], __hmul2(wk, yk2[0]));
            __half2 fv23 = __hfma2(wj, yj2[1], __hmul2(wk, yk2[1]));
            __half2 t01 = __hmul2(f01, fv01);
            __half2 t23 = __hmul2(f23, fv23);
            acc[g * 4 + 0] += __low2float(t01);
            acc[g * 4 + 1] += __high2float(t01);
            acc[g * 4 + 2] += __low2float(t23);
            acc[g * 4 + 3] += __high2float(t23);
        }
    }

    // ---- reduce over the 16 triple-lanes (l16) within each quad group ----
#pragma unroll
    for (int m = 1; m < 16; m <<= 1)
#pragma unroll
        for (int i = 0; i < 16; ++i) acc[i] += __shfl_xor(acc[i], m, 64);

    if (l16 == 0) {
#pragma unroll
        for (int g = 0; g < 4; ++g) {
            floatx4 v = {acc[g * 4 + 0], acc[g * 4 + 1], acc[g * 4 + 2], acc[g * 4 + 3]};
            *(floatx4*)&red[w][g * 16 + quad * 4] = v;
        }
    }
    __syncthreads();

    if (tid < FF)
        partial[(split * (BB * AA) + ba) * FF + tid] =
            red[0][tid] + red[1][tid] + red[2][tid] + red[3][tid];
}

// Kernel 3: sum the NSPLIT partials, f2out matvec + ssp
__global__ void out_kernel(const float* __restrict__ partial,
                           const float* __restrict__ Wf,
                           const float* __restrict__ bf,
                           float* __restrict__ out) {
    __shared__ float yag[FF];
    const int ba = blockIdx.x;
    const int t = threadIdx.x;  // 128
    if (t < FF) {
        float s = 0.f;
#pragma unroll
        for (int sp = 0; sp < NSPLIT; ++sp)
            s += partial[(sp * (BB * AA) + ba) * FF + t];
        yag[t] = s;
    }
    __syncthreads();
    float a = bf[t];
#pragma unroll 8
    for (int f = 0; f < FF; ++f) a += yag[f] * Wf[f * DOUT + t];
    out[(long)ba * DOUT + t] = ssp_f(a);
}

extern "C" void kernel_launch(void* const* d_in, const int* in_sizes, int n_in,
                              void* d_out, int out_size, void* d_ws, size_t ws_size,
                              hipStream_t stream) {
    const float* x       = (const float*)d_in[0];
    const float* r_ij    = (const float*)d_in[2];
    const float* r_ik    = (const float*)d_in[3];
    const int*   nbrj    = (const int*)d_in[7];
    const int*   nbrk    = (const int*)d_in[8];
    const float* tmask   = (const float*)d_in[9];
    const float* d_ijk   = (const float*)d_in[10];
    const float* W_in2f  = (const float*)d_in[11];
    const float* W_t1    = (const float*)d_in[12];
    const float* b_t1    = (const float*)d_in[13];
    const float* W_t2    = (const float*)d_in[14];
    const float* b_t2    = (const float*)d_in[15];
    const float* W_f2out = (const float*)d_in[16];
    const float* b_f2out = (const float*)d_in[17];
    float* out = (float*)d_out;

    char* ws = (char*)d_ws;
    _Float16* y      = (_Float16*)(ws + OFF_Y);
    float* partial   = (float*)(ws + OFF_PARTIAL);
    _Float16* B1tab  = (_Float16*)(ws + OFF_B1);
    _Float16* B2tab  = (_Float16*)(ws + OFF_B2);
    _Float16* BPtab  = (_Float16*)(ws + OFF_BP);

    in2f_prep_kernel<<<BB * AA, 64, 0, stream>>>(x, W_in2f, y, W_t1, b_t1,
                                                 W_t2, b_t2, B1tab, B2tab, BPtab);
    triple_kernel<<<BB * AA * NSPLIT, 256, 0, stream>>>(nbrj, nbrk, r_ij, r_ik,
                                                        tmask, d_ijk, B1tab, B2tab,
                                                        BPtab, y, partial);
    out_kernel<<<BB * AA, 128, 0, stream>>>(partial, W_f2out, b_f2out, out);
}

// Round 10
// 234.180 us; speedup vs baseline: 1.1134x; 1.1134x over previous
//
#include <hip/hip_runtime.h>
#include <hip/hip_fp16.h>

#define BB 2
#define AA 512
#define NN 1024
#define FF 64
#define DIN 128
#define DOUT 128
#define TH 25
#define ASTRIDE 40   // halves per a_tile row (16B-aligned frag base)
#define HSTRIDE 72   // halves per h_tile row (16B-aligned, 144B row pitch)
#define NSPLIT 2
#define NIT 8        // NN / (16 * 4 * NSPLIT) tiles per wave

typedef _Float16 half8 __attribute__((ext_vector_type(8)));
typedef _Float16 half4v __attribute__((ext_vector_type(4)));
typedef float floatx4 __attribute__((ext_vector_type(4)));

#define LOG2E 1.44269504088896f
#define LN2F  0.693147180559945f

__device__ __forceinline__ float ssp_f(float x) {
    return __logf(0.5f * __expf(x) + 0.5f);  // softplus(x) - ln2
}

__device__ __forceinline__ float cutcos(float r) {
    float c = 0.5f * (__cosf(r * (3.14159265358979323846f / 5.0f)) + 1.0f);
    return (r < 5.0f) ? c : 0.0f;
}

// folded shifted softplus: input z = a*log2e - 1 (scale/shift folded into W1/b1),
// output log2(0.5*e^a + 0.5) = ssp(a)/ln2 (ln2 folded into W2 rows).
__device__ __forceinline__ __half2 ssp2f(__half2 z) {
    const __half2 hlf = __float2half2_rn(0.5f);
    return h2log2(__hadd2(h2exp2(z), hlf));
}

// pack two f32 -> __half2 (v_cvt_pkrtz_f16_f32); bit-cast through memory
__device__ __forceinline__ __half2 pk2(float a, float b) {
    auto v = __builtin_amdgcn_cvt_pkrtz(a, b);  // __fp16 ext_vector(2)
    __half2 r;
    __builtin_memcpy(&r, &v, sizeof(r));
    return r;
}

// pack two half2 -> 4 x f16 for a single ds_write_b64
__device__ __forceinline__ half4v pack4(__half2 lo, __half2 hi) {
    half4v r;
    __builtin_memcpy(&r, &lo, 4);
    __builtin_memcpy(reinterpret_cast<char*>(&r) + 4, &hi, 4);
    return r;
}

// ---- d_ws layout (bytes) ----
#define OFF_Y       0                                              // 128 KB
#define OFF_PARTIAL (OFF_Y + (size_t)BB * AA * FF * 2)             // 512 KB (NSPLIT=2)
#define OFF_B1      (OFF_PARTIAL + (size_t)NSPLIT * BB * AA * FF * 4)
#define OFF_B2      (OFF_B1 + 4 * 64 * 8 * 2)                      // B1tab 4 KB
#define OFF_BP      (OFF_B2 + 8 * 64 * 8 * 2)                      // B2tab 8 KB; BPtab(b2) 2 KB

// Kernel 1: in2f (all blocks) + weight-fragment prep (block 0 only).
// Folds: W_t1 *= log2e; bias row k=25 of B1 = b_t1*log2e - 1 (A col 25 is 1.0),
// so mm1's f32 accumulator directly yields z for ssp2f. W_t2 *= ln2 restores scale.
__global__ void in2f_prep_kernel(const float* __restrict__ x,
                                 const float* __restrict__ Wi,
                                 _Float16* __restrict__ y,
                                 const float* __restrict__ W_t1, const float* __restrict__ b_t1,
                                 const float* __restrict__ W_t2, const float* __restrict__ b_t2,
                                 _Float16* __restrict__ B1tab, _Float16* __restrict__ B2tab,
                                 _Float16* __restrict__ BPtab) {
    __shared__ float xs[DIN];
    const int ba = blockIdx.x;
    const int t = threadIdx.x;  // 64
    xs[t] = x[ba * DIN + t];
    xs[t + 64] = x[ba * DIN + 64 + t];
    __syncthreads();
    float acc = 0.f;
#pragma unroll 8
    for (int d = 0; d < DIN; ++d) acc += xs[d] * Wi[d * FF + t];
    y[ba * FF + t] = (_Float16)acc;

    if (ba == 0) {  // prep: format MFMA fragments in per-lane layout
        const int lane = t, quad = t >> 4, l16 = t & 15;
#pragma unroll
        for (int g = 0; g < 4; ++g) {
            const int featA = g * 16 + l16;  // A-operand (M) feature of row l16
#pragma unroll
            for (int j = 0; j < 8; ++j) {
                int k = quad * 8 + j;
                _Float16 v;
                if (k < TH)       v = (_Float16)(W_t1[k * FF + featA] * LOG2E);
                else if (k == TH) v = (_Float16)(b_t1[featA] * LOG2E - 1.0f);  // bias row (A col 25 = 1)
                else              v = (_Float16)0.f;
                B1tab[(g * 64 + lane) * 8 + j] = v;
            }
            // b2 pairs: D rows 4*quad+{2e,2e+1} -> feature g*16+quad*4+...
#pragma unroll
            for (int e = 0; e < 2; ++e) {
                BPtab[((g * 2 + e) * 64 + lane) * 2 + 0] =
                    (_Float16)b_t2[g * 16 + quad * 4 + 2 * e];
                BPtab[((g * 2 + e) * 64 + lane) * 2 + 1] =
                    (_Float16)b_t2[g * 16 + quad * 4 + 2 * e + 1];
            }
            // B2 rows scaled by ln2 (h is stored as ssp/ln2)
#pragma unroll
            for (int q = 0; q < 2; ++q)
#pragma unroll
                for (int j = 0; j < 8; ++j)
                    B2tab[((g * 2 + q) * 64 + lane) * 8 + j] =
                        (_Float16)(W_t2[(q * 32 + quad * 8 + j) * FF + g * 16 + l16] * LN2F);
        }
    }
}

// Kernel 2: R6 champion structure (NSPLIT=2/NIT=8, folded ssp, LDS A-staging,
// h/f LDS trips, 16B gathers — all load-bearing per R2/R9) + the occupancy
// lever done right:
//  - packed per-lane precompute (R8-verified): -4 VGPR, fewer shfl
//  - B2 fragments in an 8 KB per-BLOCK LDS copy (shared by 4 waves), read
//    per-pair (4x ds_read_b128 + 1 wait, 2x/iter). Opacity barrier on the
//    LDS offset defeats LICM (R7 lesson: hoisting -> 32 persistent regs ->
//    forced-bound spill of 27 MB). LDS reads are ~120cy and pipeline, unlike
//    R8's serialized ~200cy global loads (R8 lesson).
// Target: natural VGPR <= 64 (R8 proved 60 reachable and occupancy 25->38%).
// NOTE: bare __launch_bounds__(256) — forcing caps spills (R7).
__global__ __launch_bounds__(256) void triple_kernel(
    const int* __restrict__ nbrj, const int* __restrict__ nbrk,
    const float* __restrict__ r_ij, const float* __restrict__ r_ik,
    const float* __restrict__ tmask, const float* __restrict__ d_ijk,
    const _Float16* __restrict__ B1tab, const _Float16* __restrict__ B2tab,
    const _Float16* __restrict__ BPtab,
    const _Float16* __restrict__ y_tab, float* __restrict__ partial) {

    // per-wave buffers -> no __syncthreads in main loop (same-wave DS is in-order)
    __shared__ __align__(16) _Float16 a_tile[4][16 * ASTRIDE];
    __shared__ __align__(16) _Float16 h_tile[4][16 * HSTRIDE];  // h, then reused for filter
    __shared__ __align__(16) _Float16 b2_lds[8 * 64 * 8];       // B2 fragments, block-shared
    __shared__ float red[4][FF];

    const int blk = blockIdx.x;
    const int ba = blk >> 1;         // NSPLIT = 2
    const int split = blk & 1;
    const int b = ba >> 9;  // A = 512
    const int tid = threadIdx.x;
    const int w = tid >> 6;
    const int lane = tid & 63;
    const int quad = lane >> 4;
    const int l16 = lane & 15;
    const int rA = lane >> 3;        // row group: rows rA and rA+8
    const int fc = (lane & 7) * 8;   // feature chunk base (8 f16)

    const long ban = (long)ba * NN;
    const float* dbase = d_ijk + (long)ba * NN * TH;
    const _Float16* yb = y_tab + (long)b * (AA * FF);

    // ---- stage B2 into block-shared LDS (once) ----
    ((half8*)b2_lds)[tid]       = ((const half8*)B2tab)[tid];
    ((half8*)b2_lds)[tid + 256] = ((const half8*)B2tab)[tid + 256];

    // ---- persistent weights: B1 (16 regs) + b2 bias pairs (4 regs) ----
    half8 B1[4];
    __half2 b2p[4][2];
#pragma unroll
    for (int g = 0; g < 4; ++g) {
        B1[g] = *(const half8*)(B1tab + (g * 64 + lane) * 8);
#pragma unroll
        for (int e = 0; e < 2; ++e)
            b2p[g][e] = *(const __half2*)(BPtab + ((g * 2 + e) * 64 + lane) * 2);
    }

    // ---- per-lane triple precompute, TWO sets, PACKED (R8-verified):
    //      set0: lane (quad,l16) owns triple l16 of tile (split*32 + quad*4 + w)
    //      set1: same for it==quad+4 (tile index +16, triple index +256)
    const int tile0 = split * 32 + quad * 4 + w;
    const long n0a = ban + (long)tile0 * 16 + l16;
    const long n1a = n0a + 256;
    int pp0, pp1, wp0, wp1;
    {
        const float rij0 = r_ij[n0a], rik0 = r_ik[n0a];
        const float rij1 = r_ij[n1a], rik1 = r_ik[n1a];
        const float iv0 = cutcos(rij0) * cutcos(rik0) * tmask[n0a] / (rij0 + rik0);
        const float iv1 = cutcos(rij1) * cutcos(rik1) * tmask[n1a] / (rij1 + rik1);
        __half2 w0 = pk2(rij0 * iv0, rik0 * iv0);
        __half2 w1 = pk2(rij1 * iv1, rik1 * iv1);
        __builtin_memcpy(&wp0, &w0, 4);
        __builtin_memcpy(&wp1, &w1, 4);
        pp0 = nbrj[n0a] | (nbrk[n0a] << 16);   // indices < 512 -> 16 bits each
        pp1 = nbrj[n1a] | (nbrk[n1a] << 16);
    }

    // A-tile K-pad: col 25 = 1.0 (bias row), cols 26..31 = 0 — written once
    for (int idx = lane; idx < 16 * 7; idx += 64) {
        int r = idx / 7, c = 25 + idx % 7;
        a_tile[w][r * ASTRIDE + c] = (c == 25) ? (_Float16)1.f : (_Float16)0.f;
    }

    // A staging map: 400 contiguous floats; 3 x float2/lane + 16-float tail
    int lofs2[3][2];
#pragma unroll
    for (int m = 0; m < 3; ++m)
#pragma unroll
        for (int e = 0; e < 2; ++e) {
            int s = m * 128 + lane * 2 + e;
            int r = s / TH, c = s - r * TH;
            lofs2[m][e] = r * ASTRIDE + c;
        }
    const int tofs = 15 * ASTRIDE + 9 + lane;  // tail: row 15 cols 9..24 (lane<16)

    float acc[8];
#pragma unroll
    for (int i = 0; i < 8; ++i) acc[i] = 0.f;
    const floatx4 zero4 = {0.f, 0.f, 0.f, 0.f};

    // ---- prologue: prefetch A tile for it=0 ----
    float2 pA[3];
    float pT = 0.f;
    const float* dp0 = dbase + (long)(split * 32 + w) * 16 * TH;
    {
#pragma unroll
        for (int m = 0; m < 3; ++m) pA[m] = *(const float2*)(dp0 + m * 128 + lane * 2);
        if (lane < 16) pT = dp0[384 + lane];
    }

    __syncthreads();  // b2_lds visible to all waves (only pre-loop block sync)

#pragma unroll 1
    for (int it = 0; it < NIT; ++it) {
        // 1. packed indices/weights via cross-lane broadcast; issue 16B gathers
        //    (8-rows-per-instruction layout — load-bearing, R2/R9 measured)
        const bool s1 = (it >= 4);
        const int sl0 = (it & 3) * 16 + rA;   // lane holding triple n0+rA
        const int sl1 = sl0 + 8;              // lane holding triple n0+rA+8
        const int ppS = s1 ? pp1 : pp0;
        const int wpS = s1 ? wp1 : wp0;
        const int ppa = __shfl(ppS, sl0), ppb = __shfl(ppS, sl1);
        const int wpa = __shfl(wpS, sl0), wpb = __shfl(wpS, sl1);
        const int pj0 = ppa & 0xffff, pk0 = ((unsigned)ppa) >> 16;
        const int pj1 = ppb & 0xffff, pk1 = ((unsigned)ppb) >> 16;
        half8 gj0 = *(const half8*)(yb + pj0 * FF + fc);
        half8 gk0 = *(const half8*)(yb + pk0 * FF + fc);
        half8 gj1 = *(const half8*)(yb + pj1 * FF + fc);
        half8 gk1 = *(const half8*)(yb + pk1 * FF + fc);

        // 2. commit prefetched A -> LDS (f32 -> f16)
#pragma unroll
        for (int m = 0; m < 3; ++m) {
            a_tile[w][lofs2[m][0]] = (_Float16)pA[m].x;
            a_tile[w][lofs2[m][1]] = (_Float16)pA[m].y;
        }
        if (lane < 16) a_tile[w][tofs] = (_Float16)pT;

        // 3. prefetch next A tile (overlaps MFMA/ssp chain); +4 tiles = +1600 floats
        if (it + 1 < NIT) {
            const float* dn = dp0 + (it + 1) * 1600;
#pragma unroll
            for (int m = 0; m < 3; ++m) pA[m] = *(const float2*)(dn + m * 128 + lane * 2);
            if (lane < 16) pT = dn[384 + lane];
        }

        // unpack interp weights (splat low/high halves)
        __half2 wv0, wv1;
        __builtin_memcpy(&wv0, &wpa, 4);
        __builtin_memcpy(&wv1, &wpb, 4);
        const __half2 wj0 = __half2half2(__low2half(wv0));
        const __half2 wk0 = __half2half2(__high2half(wv0));
        const __half2 wj1 = __half2half2(__low2half(wv1));
        const __half2 wk1 = __half2half2(__high2half(wv1));

        // 4. mm1 (swapped; bias+log2e folded into B1) + folded packed ssp
        half8 afrag = *(const half8*)&a_tile[w][l16 * ASTRIDE + quad * 8];
#pragma unroll
        for (int g = 0; g < 4; ++g) {
            floatx4 hv = __builtin_amdgcn_mfma_f32_16x16x32_f16(B1[g], afrag, zero4, 0, 0, 0);
            __half2 h01 = ssp2f(pk2(hv[0], hv[1]));
            __half2 h23 = ssp2f(pk2(hv[2], hv[3]));
            *(half4v*)&h_tile[w][l16 * HSTRIDE + g * 16 + quad * 4] = pack4(h01, h23);
        }

        // 5. mm2 (K=64, swapped; W2 pre-scaled by ln2). B2 fragments read from
        //    block-shared LDS per-pair (4 b128 + 1 wait, 16 transient regs);
        //    opacity barrier on the offset keeps the reads in-loop (anti-LICM).
        //    Filter written back into h_tile (per-wave DS program order),
        //    read back in gather layout.
        half8 a2q0 = *(const half8*)&h_tile[w][l16 * HSTRIDE + quad * 8];
        half8 a2q1 = *(const half8*)&h_tile[w][l16 * HSTRIDE + 32 + quad * 8];
        int b2o = lane * 8;
#pragma unroll
        for (int gp = 0; gp < 2; ++gp) {
            asm volatile("" : "+v"(b2o));   // opaque per pair: no hoist/merge
            const _Float16* bp = b2_lds + b2o + gp * 2048;
            half8 F00 = *(const half8*)(bp + 0 * 512);
            half8 F01 = *(const half8*)(bp + 1 * 512);
            half8 F10 = *(const half8*)(bp + 2 * 512);
            half8 F11 = *(const half8*)(bp + 3 * 512);
            {
                const int g = gp * 2;
                floatx4 w2 = __builtin_amdgcn_mfma_f32_16x16x32_f16(F00, a2q0, zero4, 0, 0, 0);
                w2 = __builtin_amdgcn_mfma_f32_16x16x32_f16(F01, a2q1, w2, 0, 0, 0);
                __half2 f01 = __hadd2(pk2(w2[0], w2[1]), b2p[g][0]);
                __half2 f23 = __hadd2(pk2(w2[2], w2[3]), b2p[g][1]);
                *(half4v*)&h_tile[w][l16 * HSTRIDE + g * 16 + quad * 4] = pack4(f01, f23);
            }
            {
                const int g = gp * 2 + 1;
                floatx4 w2 = __builtin_amdgcn_mfma_f32_16x16x32_f16(F10, a2q0, zero4, 0, 0, 0);
                w2 = __builtin_amdgcn_mfma_f32_16x16x32_f16(F11, a2q1, w2, 0, 0, 0);
                __half2 f01 = __hadd2(pk2(w2[0], w2[1]), b2p[g][0]);
                __half2 f23 = __hadd2(pk2(w2[2], w2[3]), b2p[g][1]);
                *(half4v*)&h_tile[w][l16 * HSTRIDE + g * 16 + quad * 4] = pack4(f01, f23);
            }
        }
        half8 f0 = *(const half8*)&h_tile[w][rA * HSTRIDE + fc];
        half8 f1 = *(const half8*)&h_tile[w][(8 + rA) * HSTRIDE + fc];

        // 6. epilogue: packed-f16 interp + filter-mul (2 terms only in f16),
        //    flushed to f32 accumulators every iteration
        const __half2* gj0p = (const __half2*)&gj0;
        const __half2* gk0p = (const __half2*)&gk0;
        const __half2* gj1p = (const __half2*)&gj1;
        const __half2* gk1p = (const __half2*)&gk1;
        const __half2* f0p = (const __half2*)&f0;
        const __half2* f1p = (const __half2*)&f1;
#pragma unroll
        for (int p = 0; p < 4; ++p) {
            __half2 fv0 = __hfma2(wj0, gj0p[p], __hmul2(wk0, gk0p[p]));
            __half2 fv1 = __hfma2(wj1, gj1p[p], __hmul2(wk1, gk1p[p]));
            __half2 tot = __hfma2(f1p[p], fv1, __hmul2(f0p[p], fv0));
            acc[2 * p]     += __low2float(tot);
            acc[2 * p + 1] += __high2float(tot);
        }
    }

    // ---- reduce over row-groups within wave ----
#pragma unroll
    for (int i = 0; i < 8; ++i) {
        acc[i] += __shfl_xor(acc[i], 8, 64);
        acc[i] += __shfl_xor(acc[i], 16, 64);
        acc[i] += __shfl_xor(acc[i], 32, 64);
    }
    if (lane < 8)
#pragma unroll
        for (int i = 0; i < 8; ++i) red[w][lane * 8 + i] = acc[i];
    __syncthreads();

    if (tid < FF)
        partial[(split * (BB * AA) + ba) * FF + tid] =
            red[0][tid] + red[1][tid] + red[2][tid] + red[3][tid];
}

// Kernel 3: sum the NSPLIT partials, f2out matvec + ssp
__global__ void out_kernel(const float* __restrict__ partial,
                           const float* __restrict__ Wf,
                           const float* __restrict__ bf,
                           float* __restrict__ out) {
    __shared__ float yag[FF];
    const int ba = blockIdx.x;
    const int t = threadIdx.x;  // 128
    if (t < FF) {
        float s = 0.f;
#pragma unroll
        for (int sp = 0; sp < NSPLIT; ++sp)
            s += partial[(sp * (BB * AA) + ba) * FF + t];
        yag[t] = s;
    }
    __syncthreads();
    float a = bf[t];
#pragma unroll 8
    for (int f = 0; f < FF; ++f) a += yag[f] * Wf[f * DOUT + t];
    out[(long)ba * DOUT + t] = ssp_f(a);
}

extern "C" void kernel_launch(void* const* d_in, const int* in_sizes, int n_in,
                              void* d_out, int out_size, void* d_ws, size_t ws_size,
                              hipStream_t stream) {
    const float* x       = (const float*)d_in[0];
    const float* r_ij    = (const float*)d_in[2];
    const float* r_ik    = (const float*)d_in[3];
    const int*   nbrj    = (const int*)d_in[7];
    const int*   nbrk    = (const int*)d_in[8];
    const float* tmask   = (const float*)d_in[9];
    const float* d_ijk   = (const float*)d_in[10];
    const float* W_in2f  = (const float*)d_in[11];
    const float* W_t1    = (const float*)d_in[12];
    const float* b_t1    = (const float*)d_in[13];
    const float* W_t2    = (const float*)d_in[14];
    const float* b_t2    = (const float*)d_in[15];
    const float* W_f2out = (const float*)d_in[16];
    const float* b_f2out = (const float*)d_in[17];
    float* out = (float*)d_out;

    char* ws = (char*)d_ws;
    _Float16* y      = (_Float16*)(ws + OFF_Y);
    float* partial   = (float*)(ws + OFF_PARTIAL);
    _Float16* B1tab  = (_Float16*)(ws + OFF_B1);
    _Float16* B2tab  = (_Float16*)(ws + OFF_B2);
    _Float16* BPtab  = (_Float16*)(ws + OFF_BP);

    in2f_prep_kernel<<<BB * AA, 64, 0, stream>>>(x, W_in2f, y, W_t1, b_t1,
                                                 W_t2, b_t2, B1tab, B2tab, BPtab);
    triple_kernel<<<BB * AA * NSPLIT, 256, 0, stream>>>(nbrj, nbrk, r_ij, r_ik,
                                                        tmask, d_ijk, B1tab, B2tab,
                                                        BPtab, y, partial);
    out_kernel<<<BB * AA, 128, 0, stream>>>(partial, W_f2out, b_f2out, out);
}

// Round 11
// 232.955 us; speedup vs baseline: 1.1192x; 1.0053x over previous
//
#include <hip/hip_runtime.h>
#include <hip/hip_fp16.h>

#define BB 2
#define AA 512
#define NN 1024
#define FF 64
#define DIN 128
#define DOUT 128
#define TH 25
#define ASTRIDE 40   // halves per a_tile row (16B-aligned frag base)
#define HSTRIDE 72   // halves per h_tile row (16B-aligned, 144B row pitch)
#define NSPLIT 2
#define NIT 8        // NN / (16 * 4 * NSPLIT) tiles per wave

typedef _Float16 half8 __attribute__((ext_vector_type(8)));
typedef _Float16 half4v __attribute__((ext_vector_type(4)));
typedef float floatx4 __attribute__((ext_vector_type(4)));

#define LOG2E 1.44269504088896f
#define LN2F  0.693147180559945f

__device__ __forceinline__ float ssp_f(float x) {
    return __logf(0.5f * __expf(x) + 0.5f);  // softplus(x) - ln2
}

__device__ __forceinline__ float cutcos(float r) {
    float c = 0.5f * (__cosf(r * (3.14159265358979323846f / 5.0f)) + 1.0f);
    return (r < 5.0f) ? c : 0.0f;
}

// folded shifted softplus: input z = a*log2e - 1 (scale/shift folded into W1/b1),
// output log2(0.5*e^a + 0.5) = ssp(a)/ln2 (ln2 folded into W2 rows).
__device__ __forceinline__ __half2 ssp2f(__half2 z) {
    const __half2 hlf = __float2half2_rn(0.5f);
    return h2log2(__hadd2(h2exp2(z), hlf));
}

// pack two f32 -> __half2 (v_cvt_pkrtz_f16_f32); bit-cast through memory
__device__ __forceinline__ __half2 pk2(float a, float b) {
    auto v = __builtin_amdgcn_cvt_pkrtz(a, b);  // __fp16 ext_vector(2)
    __half2 r;
    __builtin_memcpy(&r, &v, sizeof(r));
    return r;
}

// pack two half2 -> 4 x f16 for a single ds_write_b64
__device__ __forceinline__ half4v pack4(__half2 lo, __half2 hi) {
    half4v r;
    __builtin_memcpy(&r, &lo, 4);
    __builtin_memcpy(reinterpret_cast<char*>(&r) + 4, &hi, 4);
    return r;
}

// ---- d_ws layout (bytes) ----
#define OFF_Y       0                                              // 128 KB
#define OFF_PARTIAL (OFF_Y + (size_t)BB * AA * FF * 2)             // 512 KB (NSPLIT=2)
#define OFF_B1      (OFF_PARTIAL + (size_t)NSPLIT * BB * AA * FF * 4)
#define OFF_B2      (OFF_B1 + 4 * 64 * 8 * 2)                      // B1tab 4 KB
#define OFF_BP      (OFF_B2 + 8 * 64 * 8 * 2)                      // B2tab 8 KB; BPtab(b2) 2 KB

// Kernel 1: in2f (all blocks) + weight-fragment prep (block 0 only).
// Folds: W_t1 *= log2e; bias row k=25 of B1 = b_t1*log2e - 1 (A col 25 is 1.0),
// so mm1's f32 accumulator directly yields z for ssp2f. W_t2 *= ln2 restores scale.
__global__ void in2f_prep_kernel(const float* __restrict__ x,
                                 const float* __restrict__ Wi,
                                 _Float16* __restrict__ y,
                                 const float* __restrict__ W_t1, const float* __restrict__ b_t1,
                                 const float* __restrict__ W_t2, const float* __restrict__ b_t2,
                                 _Float16* __restrict__ B1tab, _Float16* __restrict__ B2tab,
                                 _Float16* __restrict__ BPtab) {
    __shared__ float xs[DIN];
    const int ba = blockIdx.x;
    const int t = threadIdx.x;  // 64
    xs[t] = x[ba * DIN + t];
    xs[t + 64] = x[ba * DIN + 64 + t];
    __syncthreads();
    float acc = 0.f;
#pragma unroll 8
    for (int d = 0; d < DIN; ++d) acc += xs[d] * Wi[d * FF + t];
    y[ba * FF + t] = (_Float16)acc;

    if (ba == 0) {  // prep: format MFMA fragments in per-lane layout
        const int lane = t, quad = t >> 4, l16 = t & 15;
#pragma unroll
        for (int g = 0; g < 4; ++g) {
            const int featA = g * 16 + l16;  // A-operand (M) feature of row l16
#pragma unroll
            for (int j = 0; j < 8; ++j) {
                int k = quad * 8 + j;
                _Float16 v;
                if (k < TH)       v = (_Float16)(W_t1[k * FF + featA] * LOG2E);
                else if (k == TH) v = (_Float16)(b_t1[featA] * LOG2E - 1.0f);  // bias row (A col 25 = 1)
                else              v = (_Float16)0.f;
                B1tab[(g * 64 + lane) * 8 + j] = v;
            }
            // b2 pairs: D rows 4*quad+{2e,2e+1} -> feature g*16+quad*4+...
#pragma unroll
            for (int e = 0; e < 2; ++e) {
                BPtab[((g * 2 + e) * 64 + lane) * 2 + 0] =
                    (_Float16)b_t2[g * 16 + quad * 4 + 2 * e];
                BPtab[((g * 2 + e) * 64 + lane) * 2 + 1] =
                    (_Float16)b_t2[g * 16 + quad * 4 + 2 * e + 1];
            }
            // B2 rows scaled by ln2 (h is stored as ssp/ln2)
#pragma unroll
            for (int q = 0; q < 2; ++q)
#pragma unroll
                for (int j = 0; j < 8; ++j)
                    B2tab[((g * 2 + q) * 64 + lane) * 8 + j] =
                        (_Float16)(W_t2[(q * 32 + quad * 8 + j) * FF + g * 16 + l16] * LN2F);
        }
    }
}

// Kernel 2: R6 champion (NSPLIT=2/NIT=8, folded ssp, LDS A-staging, h/f LDS
// trips, 16B gathers — all load-bearing per R2/R9) + two chain-shorteners:
//  - DOUBLE-BUFFERED a_tile: commit tile it+1 into buf^1 right after reading
//    afrag(it) from buf -> the ds_write->ds_read stall (exposed every iter in
//    R6) now spans the whole mm1+mm2+epilogue. Global d-prefetch at distance 2.
//  - s_setprio(1) around the MFMA/ssp cluster: waves here are barrier-free and
//    independently phased (the T5-positive regime), so priority lets a
//    compute-phase wave preempt issue from staging-phase waves.
//  - packed per-lane precompute (R8-verified): 4 shfl/iter instead of 8.
// NOTE: bare __launch_bounds__(256) — forcing caps spills (R7: 27 MB scratch).
__global__ __launch_bounds__(256) void triple_kernel(
    const int* __restrict__ nbrj, const int* __restrict__ nbrk,
    const float* __restrict__ r_ij, const float* __restrict__ r_ik,
    const float* __restrict__ tmask, const float* __restrict__ d_ijk,
    const _Float16* __restrict__ B1tab, const _Float16* __restrict__ B2tab,
    const _Float16* __restrict__ BPtab,
    const _Float16* __restrict__ y_tab, float* __restrict__ partial) {

    // per-wave buffers -> no __syncthreads in main loop (same-wave DS is in-order)
    __shared__ __align__(16) _Float16 a_tile[4][2][16 * ASTRIDE];  // double-buffered
    __shared__ __align__(16) _Float16 h_tile[4][16 * HSTRIDE];  // h, then reused for filter
    __shared__ float red[4][FF];

    const int blk = blockIdx.x;
    const int ba = blk >> 1;         // NSPLIT = 2
    const int split = blk & 1;
    const int b = ba >> 9;  // A = 512
    const int tid = threadIdx.x;
    const int w = tid >> 6;
    const int lane = tid & 63;
    const int quad = lane >> 4;
    const int l16 = lane & 15;
    const int rA = lane >> 3;        // row group: rows rA and rA+8
    const int fc = (lane & 7) * 8;   // feature chunk base (8 f16)

    const long ban = (long)ba * NN;
    const float* dbase = d_ijk + (long)ba * NN * TH;
    const _Float16* yb = y_tab + (long)b * (AA * FF);

    // ---- weight fragments: pre-formatted vector loads; b2 pairs as half2 ----
    half8 B1[4];
    half8 B2[4][2];
    __half2 b2p[4][2];
#pragma unroll
    for (int g = 0; g < 4; ++g) {
        B1[g] = *(const half8*)(B1tab + (g * 64 + lane) * 8);
        B2[g][0] = *(const half8*)(B2tab + ((g * 2 + 0) * 64 + lane) * 8);
        B2[g][1] = *(const half8*)(B2tab + ((g * 2 + 1) * 64 + lane) * 8);
#pragma unroll
        for (int e = 0; e < 2; ++e)
            b2p[g][e] = *(const __half2*)(BPtab + ((g * 2 + e) * 64 + lane) * 2);
    }

    // ---- per-lane triple precompute, TWO sets, PACKED (R8-verified):
    //      set0: lane (quad,l16) owns triple l16 of tile (split*32 + quad*4 + w)
    //      set1: same for it==quad+4 (tile index +16, triple index +256)
    const int tile0 = split * 32 + quad * 4 + w;
    const long n0a = ban + (long)tile0 * 16 + l16;
    const long n1a = n0a + 256;
    int pp0, pp1, wp0, wp1;
    {
        const float rij0 = r_ij[n0a], rik0 = r_ik[n0a];
        const float rij1 = r_ij[n1a], rik1 = r_ik[n1a];
        const float iv0 = cutcos(rij0) * cutcos(rik0) * tmask[n0a] / (rij0 + rik0);
        const float iv1 = cutcos(rij1) * cutcos(rik1) * tmask[n1a] / (rij1 + rik1);
        __half2 w0 = pk2(rij0 * iv0, rik0 * iv0);
        __half2 w1 = pk2(rij1 * iv1, rik1 * iv1);
        __builtin_memcpy(&wp0, &w0, 4);
        __builtin_memcpy(&wp1, &w1, 4);
        pp0 = nbrj[n0a] | (nbrk[n0a] << 16);   // indices < 512 -> 16 bits each
        pp1 = nbrj[n1a] | (nbrk[n1a] << 16);
    }

    // A-tile K-pad (both buffers): col 25 = 1.0 (bias row), 26..31 = 0 — once
    for (int idx = lane; idx < 16 * 7; idx += 64) {
        int r = idx / 7, c = 25 + idx % 7;
        _Float16 v = (c == 25) ? (_Float16)1.f : (_Float16)0.f;
        a_tile[w][0][r * ASTRIDE + c] = v;
        a_tile[w][1][r * ASTRIDE + c] = v;
    }

    // A staging map: 400 contiguous floats; 3 x float2/lane + 16-float tail
    int lofs2[3][2];
#pragma unroll
    for (int m = 0; m < 3; ++m)
#pragma unroll
        for (int e = 0; e < 2; ++e) {
            int s = m * 128 + lane * 2 + e;
            int r = s / TH, c = s - r * TH;
            lofs2[m][e] = r * ASTRIDE + c;
        }
    const int tofs = 15 * ASTRIDE + 9 + lane;  // tail: row 15 cols 9..24 (lane<16)

    float acc[8];
#pragma unroll
    for (int i = 0; i < 8; ++i) acc[i] = 0.f;
    const floatx4 zero4 = {0.f, 0.f, 0.f, 0.f};

    // ---- prologue: commit tile 0 into buf0; hold tile 1 in regs ----
    float2 pA[3];
    float pT = 0.f;
    const float* dp0 = dbase + (long)(split * 32 + w) * 16 * TH;
    {
#pragma unroll
        for (int m = 0; m < 3; ++m) pA[m] = *(const float2*)(dp0 + m * 128 + lane * 2);
        if (lane < 16) pT = dp0[384 + lane];
#pragma unroll
        for (int m = 0; m < 3; ++m) {
            a_tile[w][0][lofs2[m][0]] = (_Float16)pA[m].x;
            a_tile[w][0][lofs2[m][1]] = (_Float16)pA[m].y;
        }
        if (lane < 16) a_tile[w][0][tofs] = (_Float16)pT;
        const float* d1 = dp0 + 1600;
#pragma unroll
        for (int m = 0; m < 3; ++m) pA[m] = *(const float2*)(d1 + m * 128 + lane * 2);
        if (lane < 16) pT = d1[384 + lane];
    }

#pragma unroll 1
    for (int it = 0; it < NIT; ++it) {
        const int cur = it & 1;

        // 1. packed indices/weights via cross-lane broadcast; issue 16B gathers
        //    (8-rows-per-instruction layout — load-bearing, R2/R9 measured)
        const bool s1 = (it >= 4);
        const int sl0 = (it & 3) * 16 + rA;   // lane holding triple n0+rA
        const int sl1 = sl0 + 8;              // lane holding triple n0+rA+8
        const int ppS = s1 ? pp1 : pp0;
        const int wpS = s1 ? wp1 : wp0;
        const int ppa = __shfl(ppS, sl0), ppb = __shfl(ppS, sl1);
        const int wpa = __shfl(wpS, sl0), wpb = __shfl(wpS, sl1);
        const int pj0 = ppa & 0xffff, pk0 = ((unsigned)ppa) >> 16;
        const int pj1 = ppb & 0xffff, pk1 = ((unsigned)ppb) >> 16;
        half8 gj0 = *(const half8*)(yb + pj0 * FF + fc);
        half8 gk0 = *(const half8*)(yb + pk0 * FF + fc);
        half8 gj1 = *(const half8*)(yb + pj1 * FF + fc);
        half8 gk1 = *(const half8*)(yb + pk1 * FF + fc);

        // 2. read afrag for THIS tile (writes for it happened one iter ago ->
        //    the ds_write->ds_read latency is already paid)
        half8 afrag = *(const half8*)&a_tile[w][cur][l16 * ASTRIDE + quad * 8];

        // 3. commit the register-held NEXT tile into the other buffer
        //    (read at it+1, a full mm1+mm2+epilogue away)
        if (it + 1 < NIT) {
#pragma unroll
            for (int m = 0; m < 3; ++m) {
                a_tile[w][cur ^ 1][lofs2[m][0]] = (_Float16)pA[m].x;
                a_tile[w][cur ^ 1][lofs2[m][1]] = (_Float16)pA[m].y;
            }
            if (lane < 16) a_tile[w][cur ^ 1][tofs] = (_Float16)pT;
        }

        // 4. prefetch tile it+2 from global (a full iteration to complete)
        if (it + 2 < NIT) {
            const float* dn = dp0 + (it + 2) * 1600;
#pragma unroll
            for (int m = 0; m < 3; ++m) pA[m] = *(const float2*)(dn + m * 128 + lane * 2);
            if (lane < 16) pT = dn[384 + lane];
        }

        // unpack interp weights (splat low/high halves)
        __half2 wv0, wv1;
        __builtin_memcpy(&wv0, &wpa, 4);
        __builtin_memcpy(&wv1, &wpb, 4);
        const __half2 wj0 = __half2half2(__low2half(wv0));
        const __half2 wk0 = __half2half2(__high2half(wv0));
        const __half2 wj1 = __half2half2(__low2half(wv1));
        const __half2 wk1 = __half2half2(__high2half(wv1));

        // 5. mm1 (swapped; bias+log2e folded into B1) + folded packed ssp,
        //    then mm2 — the whole compute cluster runs at raised priority
        //    (independent-phase waves: the T5-positive regime)
        __builtin_amdgcn_s_setprio(1);
#pragma unroll
        for (int g = 0; g < 4; ++g) {
            floatx4 hv = __builtin_amdgcn_mfma_f32_16x16x32_f16(B1[g], afrag, zero4, 0, 0, 0);
            __half2 h01 = ssp2f(pk2(hv[0], hv[1]));
            __half2 h23 = ssp2f(pk2(hv[2], hv[3]));
            *(half4v*)&h_tile[w][l16 * HSTRIDE + g * 16 + quad * 4] = pack4(h01, h23);
        }

        // mm2 (K=64, swapped; W2 pre-scaled by ln2); filter written back into
        // h_tile (safe: per-wave DS program order), read back in gather layout
        half8 a2q0 = *(const half8*)&h_tile[w][l16 * HSTRIDE + quad * 8];
        half8 a2q1 = *(const half8*)&h_tile[w][l16 * HSTRIDE + 32 + quad * 8];
#pragma unroll
        for (int g = 0; g < 4; ++g) {
            floatx4 w2 = __builtin_amdgcn_mfma_f32_16x16x32_f16(B2[g][0], a2q0, zero4, 0, 0, 0);
            w2 = __builtin_amdgcn_mfma_f32_16x16x32_f16(B2[g][1], a2q1, w2, 0, 0, 0);
            __half2 f01 = __hadd2(pk2(w2[0], w2[1]), b2p[g][0]);
            __half2 f23 = __hadd2(pk2(w2[2], w2[3]), b2p[g][1]);
            *(half4v*)&h_tile[w][l16 * HSTRIDE + g * 16 + quad * 4] = pack4(f01, f23);
        }
        __builtin_amdgcn_s_setprio(0);
        half8 f0 = *(const half8*)&h_tile[w][rA * HSTRIDE + fc];
        half8 f1 = *(const half8*)&h_tile[w][(8 + rA) * HSTRIDE + fc];

        // 6. epilogue: packed-f16 interp + filter-mul (2 terms only in f16),
        //    flushed to f32 accumulators every iteration
        const __half2* gj0p = (const __half2*)&gj0;
        const __half2* gk0p = (const __half2*)&gk0;
        const __half2* gj1p = (const __half2*)&gj1;
        const __half2* gk1p = (const __half2*)&gk1;
        const __half2* f0p = (const __half2*)&f0;
        const __half2* f1p = (const __half2*)&f1;
#pragma unroll
        for (int p = 0; p < 4; ++p) {
            __half2 fv0 = __hfma2(wj0, gj0p[p], __hmul2(wk0, gk0p[p]));
            __half2 fv1 = __hfma2(wj1, gj1p[p], __hmul2(wk1, gk1p[p]));
            __half2 tot = __hfma2(f1p[p], fv1, __hmul2(f0p[p], fv0));
            acc[2 * p]     += __low2float(tot);
            acc[2 * p + 1] += __high2float(tot);
        }
    }

    // ---- reduce over row-groups within wave ----
#pragma unroll
    for (int i = 0; i < 8; ++i) {
        acc[i] += __shfl_xor(acc[i], 8, 64);
        acc[i] += __shfl_xor(acc[i], 16, 64);
        acc[i] += __shfl_xor(acc[i], 32, 64);
    }
    if (lane < 8)
#pragma unroll
        for (int i = 0; i < 8; ++i) red[w][lane * 8 + i] = acc[i];
    __syncthreads();

    if (tid < FF)
        partial[(split * (BB * AA) + ba) * FF + tid] =
            red[0][tid] + red[1][tid] + red[2][tid] + red[3][tid];
}

// Kernel 3: sum the NSPLIT partials, f2out matvec + ssp
__global__ void out_kernel(const float* __restrict__ partial,
                           const float* __restrict__ Wf,
                           const float* __restrict__ bf,
                           float* __restrict__ out) {
    __shared__ float yag[FF];
    const int ba = blockIdx.x;
    const int t = threadIdx.x;  // 128
    if (t < FF) {
        float s = 0.f;
#pragma unroll
        for (int sp = 0; sp < NSPLIT; ++sp)
            s += partial[(sp * (BB * AA) + ba) * FF + t];
        yag[t] = s;
    }
    __syncthreads();
    float a = bf[t];
#pragma unroll 8
    for (int f = 0; f < FF; ++f) a += yag[f] * Wf[f * DOUT + t];
    out[(long)ba * DOUT + t] = ssp_f(a);
}

extern "C" void kernel_launch(void* const* d_in, const int* in_sizes, int n_in,
                              void* d_out, int out_size, void* d_ws, size_t ws_size,
                              hipStream_t stream) {
    const float* x       = (const float*)d_in[0];
    const float* r_ij    = (const float*)d_in[2];
    const float* r_ik    = (const float*)d_in[3];
    const int*   nbrj    = (const int*)d_in[7];
    const int*   nbrk    = (const int*)d_in[8];
    const float* tmask   = (const float*)d_in[9];
    const float* d_ijk   = (const float*)d_in[10];
    const float* W_in2f  = (const float*)d_in[11];
    const float* W_t1    = (const float*)d_in[12];
    const float* b_t1    = (const float*)d_in[13];
    const float* W_t2    = (const float*)d_in[14];
    const float* b_t2    = (const float*)d_in[15];
    const float* W_f2out = (const float*)d_in[16];
    const float* b_f2out = (const float*)d_in[17];
    float* out = (float*)d_out;

    char* ws = (char*)d_ws;
    _Float16* y      = (_Float16*)(ws + OFF_Y);
    float* partial   = (float*)(ws + OFF_PARTIAL);
    _Float16* B1tab  = (_Float16*)(ws + OFF_B1);
    _Float16* B2tab  = (_Float16*)(ws + OFF_B2);
    _Float16* BPtab  = (_Float16*)(ws + OFF_BP);

    in2f_prep_kernel<<<BB * AA, 64, 0, stream>>>(x, W_in2f, y, W_t1, b_t1,
                                                 W_t2, b_t2, B1tab, B2tab, BPtab);
    triple_kernel<<<BB * AA * NSPLIT, 256, 0, stream>>>(nbrj, nbrk, r_ij, r_ik,
                                                        tmask, d_ijk, B1tab, B2tab,
                                                        BPtab, y, partial);
    out_kernel<<<BB * AA, 128, 0, stream>>>(partial, W_f2out, b_f2out, out);
}